// Round 8
// baseline (1664.425 us; speedup 1.0000x reference)
//
#include <hip/hip_runtime.h>
#include <hip/hip_fp16.h>
#include <stdint.h>

#define DD 256
#define BK_SHIFT 9             // 512 slots per bucket
#define SLOTS_PER_BK 512
#define NB 196                 // ceil(100000/512) buckets
#define CHUNK 4096             // edges per coarse-scatter block
#define CSHIFT 12              // 4096 cols per phase slice (~2.1 MB fp16)
#define NPH 13                 // ceil(50000/4096) phases
#define BPS 16                 // bins per slot (13 active)
#define RPW 9                  // rows per wave
#define WPB 8                  // waves per block (512 threads)
#define RPB (RPW * WPB)        // 72 rows per block

// ext_vector types accepted by __builtin_nontemporal_*
typedef float    fx4 __attribute__((ext_vector_type(4)));
typedef uint32_t ux2 __attribute__((ext_vector_type(2)));

// ---------------- Threefry-2x32 (bit-exact JAX) ----------------
__host__ __device__ __forceinline__ uint32_t rotl32(uint32_t v, int r) {
  return (v << r) | (v >> (32 - r));
}

__host__ __device__ inline void tf2x32(uint32_t k0, uint32_t k1,
                                       uint32_t& x0, uint32_t& x1) {
  uint32_t ks0 = k0, ks1 = k1, ks2 = k0 ^ k1 ^ 0x1BD11BDAu;
  x0 += ks0; x1 += ks1;
#define TF_RND(r) { x0 += x1; x1 = rotl32(x1, (r)); x1 ^= x0; }
  TF_RND(13) TF_RND(15) TF_RND(26) TF_RND(6)
  x0 += ks1; x1 += ks2 + 1u;
  TF_RND(17) TF_RND(29) TF_RND(16) TF_RND(24)
  x0 += ks2; x1 += ks0 + 2u;
  TF_RND(13) TF_RND(15) TF_RND(26) TF_RND(6)
  x0 += ks0; x1 += ks1 + 3u;
  TF_RND(17) TF_RND(29) TF_RND(16) TF_RND(24)
  x0 += ks1; x1 += ks2 + 4u;
  TF_RND(13) TF_RND(15) TF_RND(26) TF_RND(6)
  x0 += ks2; x1 += ks0 + 5u;
#undef TF_RND
}

__device__ __forceinline__ float2 h2f(uint32_t u) {
  __half2 h = *(__half2*)&u;
  return __half22float2(h);
}

// ---------------- init: x0 = fp16(p) ----------------
__global__ void init_kernel(const float* __restrict__ p, uint32_t* __restrict__ xh,
                            int total4) {
  int t4 = blockIdx.x * blockDim.x + threadIdx.x;
  if (t4 >= total4) return;
  fx4 v = __builtin_nontemporal_load((const fx4*)p + t4);
  __half2 h0 = __floats2half2_rn(v.x, v.y);
  __half2 h1 = __floats2half2_rn(v.z, v.w);
  ux2 u;
  u.x = *(const uint32_t*)&h0;
  u.y = *(const uint32_t*)&h1;
  __builtin_nontemporal_store(u, (ux2*)xh + t4);
}

// ---------------- K1: bucket histogram (LDS-aggregated) ----------------
__global__ __launch_bounds__(256) void bucket_hist(
    const int* __restrict__ t_row, int nnz_t,
    const int* __restrict__ s_row, int nnz_s,
    int* __restrict__ gbcnt, int H) {
  __shared__ int lcnt[NB];
  for (int i = threadIdx.x; i < NB; i += 256) lcnt[i] = 0;
  __syncthreads();
  const int base = blockIdx.x * CHUNK;
  const int nnz_all = nnz_t + nnz_s;
#pragma unroll
  for (int k = 0; k < CHUNK / 256; ++k) {
    int e = base + k * 256 + threadIdx.x;
    if (e < nnz_all) {
      int slot = (e < nnz_t) ? t_row[e] : (H + s_row[e - nnz_t]);
      atomicAdd(&lcnt[slot >> BK_SHIFT], 1);
    }
  }
  __syncthreads();
  for (int i = threadIdx.x; i < NB; i += 256)
    if (lcnt[i]) atomicAdd(&gbcnt[i], lcnt[i]);
}

// ---------------- K2: bucket scan + cursor init ----------------
__global__ void bucket_scan(const int* __restrict__ gbcnt,
                            int* __restrict__ bbase, int* __restrict__ gcur) {
  if (threadIdx.x == 0) {
    int run = 0;
    for (int i = 0; i < NB; ++i) { bbase[i] = run; gcur[i] = run; run += gbcnt[i]; }
    bbase[NB] = run;
  }
}

// ---------------- K3: coarse scatter into bucket-major staging ----------------
// record = (slot << 32) | (col16 << 16) | val_fp16
__global__ __launch_bounds__(256) void coarse_scatter(
    const int* __restrict__ t_row, const int* __restrict__ t_col,
    const float* __restrict__ t_val, int nnz_t,
    const int* __restrict__ s_row, const int* __restrict__ s_col,
    const float* __restrict__ s_val, int nnz_s,
    int* __restrict__ gcur, uint64_t* __restrict__ staging, int H) {
  __shared__ int lcnt[NB], lbase[NB], gofs[NB];
  __shared__ int ltotal;
  __shared__ uint64_t stage[CHUNK];
  const int tid = threadIdx.x;
  for (int i = tid; i < NB; i += 256) lcnt[i] = 0;
  __syncthreads();
  const int base = blockIdx.x * CHUNK;
  const int nnz_all = nnz_t + nnz_s;
  uint64_t rec[CHUNK / 256];
#pragma unroll
  for (int k = 0; k < CHUNK / 256; ++k) {
    int e = base + k * 256 + tid;
    if (e < nnz_all) {
      int slot, col; float val;
      if (e < nnz_t) { slot = t_row[e]; col = t_col[e]; val = t_val[e]; }
      else { int i2 = e - nnz_t; slot = H + s_row[i2]; col = s_col[i2]; val = s_val[i2]; }
      uint32_t packed = ((uint32_t)col << 16) |
                        (uint32_t)__half_as_ushort(__float2half_rn(val));
      rec[k] = ((uint64_t)(uint32_t)slot << 32) | packed;
      atomicAdd(&lcnt[slot >> BK_SHIFT], 1);
    } else {
      rec[k] = ~0ull;
    }
  }
  __syncthreads();
  if (tid == 0) {
    int run = 0;
    for (int i = 0; i < NB; ++i) { lbase[i] = run; run += lcnt[i]; }
    ltotal = run;
  }
  __syncthreads();
  if (tid < NB) {
    if (lcnt[tid]) gofs[tid] = atomicAdd(&gcur[tid], lcnt[tid]);
    lcnt[tid] = 0;
  }
  __syncthreads();
#pragma unroll
  for (int k = 0; k < CHUNK / 256; ++k) {
    int slot = (int)(rec[k] >> 32);
    if (slot >= 0) {
      int b = slot >> BK_SHIFT;
      int p = atomicAdd(&lcnt[b], 1);
      stage[lbase[b] + p] = rec[k];
    }
  }
  __syncthreads();
  const int tot = ltotal;
  for (int i = tid; i < tot; i += 256) {
    uint64_t r = stage[i];
    int b = (int)(r >> 32) >> BK_SHIFT;
    staging[(size_t)gofs[b] + (i - lbase[b])] = r;
  }
}

// ---------------- K4: fine scatter, (slot, col-slice)-binned, writes boffs ----------
__global__ __launch_bounds__(256) void fine_scatter(
    const uint64_t* __restrict__ staging, const int* __restrict__ bbase,
    int* __restrict__ boffs, uint32_t* __restrict__ epk, int slots) {
  __shared__ int scnt[SLOTS_PER_BK * BPS];   // 8192
  __shared__ int sofs[SLOTS_PER_BK * BPS];
  __shared__ int wsum[4];
  const int b = blockIdx.x;
  const int bb = bbase[b], be = bbase[b + 1];
  const int tid = threadIdx.x;
  for (int i = tid; i < SLOTS_PER_BK * BPS; i += 256) scnt[i] = 0;
  __syncthreads();
  for (int i = bb + tid; i < be; i += 256) {
    uint64_t r = staging[i];
    int slot = (int)(r >> 32);
    int col = (int)(((uint32_t)r) >> 16);
    int bin = ((slot & (SLOTS_PER_BK - 1)) << 4) | (col >> CSHIFT);
    atomicAdd(&scnt[bin], 1);
  }
  __syncthreads();
  // exclusive scan of 8192 bins, 32 per thread
  const int base32 = tid * 32;
  int tsum = 0;
#pragma unroll
  for (int k = 0; k < 32; ++k) tsum += scnt[base32 + k];
  int lane = tid & 63, wv = tid >> 6;
  int inc = tsum;
  for (int off = 1; off < 64; off <<= 1) {
    int up = __shfl_up(inc, off, 64);
    if (lane >= off) inc += up;
  }
  if (lane == 63) wsum[wv] = inc;
  __syncthreads();
  int wbase = 0;
  for (int w = 0; w < wv; ++w) wbase += wsum[w];
  int run = wbase + inc - tsum;
#pragma unroll
  for (int k = 0; k < 32; ++k) { int v = scnt[base32 + k]; sofs[base32 + k] = run; run += v; }
  __syncthreads();
  // publish bin STARTS (global epk coordinates); gbin = slot*16 + slice
  const int gb0 = b * (SLOTS_PER_BK * BPS);
  const int nbins_total = slots * BPS;
  for (int i = tid; i < SLOTS_PER_BK * BPS; i += 256) {
    int g = gb0 + i;
    if (g < nbins_total) boffs[g] = bb + sofs[i];
  }
  __syncthreads();
  // place (4B writes inside this bucket's ~65KB epk window -> L2-local)
  for (int i = bb + tid; i < be; i += 256) {
    uint64_t r = staging[i];
    int slot = (int)(r >> 32);
    uint32_t packed = (uint32_t)r;
    int bin = ((slot & (SLOTS_PER_BK - 1)) << 4) | ((int)(packed >> 16) >> CSHIFT);
    int p = atomicAdd(&sofs[bin], 1);
    epk[(size_t)bb + p] = packed;
  }
}

// ---------------- segment gather: [sb, se) edges into acc ----------------
#define SEG_GATHER(SRC, ACC)                                                      \
  {                                                                               \
    int i = sb;                                                                   \
    for (; i + 3 < se; i += 4) {                                                  \
      uint32_t E0 = __builtin_nontemporal_load(ep + i);                           \
      uint32_t E1 = __builtin_nontemporal_load(ep + i + 1);                       \
      uint32_t E2 = __builtin_nontemporal_load(ep + i + 2);                       \
      uint32_t E3 = __builtin_nontemporal_load(ep + i + 3);                       \
      uint2 A0 = SRC[(size_t)(E0 >> 16) * 64 + lane];                             \
      uint2 A1 = SRC[(size_t)(E1 >> 16) * 64 + lane];                             \
      uint2 A2 = SRC[(size_t)(E2 >> 16) * 64 + lane];                             \
      uint2 A3 = SRC[(size_t)(E3 >> 16) * 64 + lane];                             \
      float v0 = __half2float(__ushort_as_half((unsigned short)(E0 & 0xFFFFu)));  \
      float v1 = __half2float(__ushort_as_half((unsigned short)(E1 & 0xFFFFu)));  \
      float v2 = __half2float(__ushort_as_half((unsigned short)(E2 & 0xFFFFu)));  \
      float v3 = __half2float(__ushort_as_half((unsigned short)(E3 & 0xFFFFu)));  \
      float2 f0, f1;                                                              \
      f0 = h2f(A0.x); f1 = h2f(A0.y);                                             \
      ACC.x += v0 * f0.x; ACC.y += v0 * f0.y; ACC.z += v0 * f1.x; ACC.w += v0 * f1.y; \
      f0 = h2f(A1.x); f1 = h2f(A1.y);                                             \
      ACC.x += v1 * f0.x; ACC.y += v1 * f0.y; ACC.z += v1 * f1.x; ACC.w += v1 * f1.y; \
      f0 = h2f(A2.x); f1 = h2f(A2.y);                                             \
      ACC.x += v2 * f0.x; ACC.y += v2 * f0.y; ACC.z += v2 * f1.x; ACC.w += v2 * f1.y; \
      f0 = h2f(A3.x); f1 = h2f(A3.y);                                             \
      ACC.x += v3 * f0.x; ACC.y += v3 * f0.y; ACC.z += v3 * f1.x; ACC.w += v3 * f1.y; \
    }                                                                             \
    for (; i < se; ++i) {                                                         \
      uint32_t E0 = __builtin_nontemporal_load(ep + i);                           \
      uint2 A0 = SRC[(size_t)(E0 >> 16) * 64 + lane];                             \
      float v0 = __half2float(__ushort_as_half((unsigned short)(E0 & 0xFFFFu)));  \
      float2 f0 = h2f(A0.x), f1 = h2f(A0.y);                                      \
      ACC.x += v0 * f0.x; ACC.y += v0 * f0.y; ACC.z += v0 * f1.x; ACC.w += v0 * f1.y; \
    }                                                                             \
  }

// phase-loop accumulate for this wave's RPW rows
#define PHASE_ACCUM(SRC)                                                          \
  float4 acc[RPW];                                                                \
  _Pragma("unroll")                                                               \
  for (int k = 0; k < RPW; ++k) acc[k] = make_float4(0.f, 0.f, 0.f, 0.f);         \
  for (int o = 0; o < NPH; ++o) {                                                 \
    _Pragma("unroll")                                                             \
    for (int k = 0; k < RPW; ++k) {                                               \
      int r = r0 + k;                                                             \
      if (r < nrows) {                                                            \
        int gb = (grow_base + r) * BPS + o;                                       \
        int sb = __builtin_nontemporal_load(boffs + gb);                          \
        int se = __builtin_nontemporal_load(boffs + gb + 1);                      \
        SEG_GATHER(SRC, acc[k])                                                   \
      }                                                                           \
    }                                                                             \
  }

// ---------------- persistent phase-synced SpMM ----------------
__global__ __launch_bounds__(512, 6) void spmm_phase(
    const int* __restrict__ boffs, const uint32_t* __restrict__ ep,
    const uint2* __restrict__ X, uint2* __restrict__ Y, int nrows, int grow_base) {
  const int w = threadIdx.x >> 6, lane = threadIdx.x & 63;
  const int r0 = blockIdx.x * RPB + w * RPW;
  PHASE_ACCUM(X)
#pragma unroll
  for (int k = 0; k < RPW; ++k) {
    int r = r0 + k;
    if (r >= nrows) break;
    __half2 o0 = __floats2half2_rn(acc[k].x, acc[k].y);
    __half2 o1 = __floats2half2_rn(acc[k].z, acc[k].w);
    ux2 o;
    o.x = *(const uint32_t*)&o0;
    o.y = *(const uint32_t*)&o1;
    __builtin_nontemporal_store(o, (ux2*)Y + (size_t)r * 64 + lane);
  }
}

// ---------------- persistent SpMM + residual + dropout (layers 1,2) ----------------
__global__ __launch_bounds__(512, 6) void spmm_drop_phase(
    const int* __restrict__ boffs, const uint32_t* __restrict__ ep,
    const uint2* __restrict__ T, const uint2* __restrict__ xprev,
    uint2* __restrict__ xout, uint32_t k0, uint32_t k1, int nrows, int grow_base) {
  const int w = threadIdx.x >> 6, lane = threadIdx.x & 63;
  const int r0 = blockIdx.x * RPB + w * RPW;
  PHASE_ACCUM(T)
#pragma unroll
  for (int k = 0; k < RPW; ++k) {
    int r = r0 + k;
    if (r >= nrows) break;
    size_t xi = (size_t)r * 64 + lane;
    ux2 xv = __builtin_nontemporal_load((const ux2*)xprev + xi);
    float2 p0 = h2f(xv.x), p1 = h2f(xv.y);
    float h[4] = {acc[k].x + p0.x, acc[k].y + p0.y, acc[k].z + p1.x, acc[k].w + p1.y};
    int j0 = r * DD + lane * 4;
    float xn[4];
#pragma unroll
    for (int q = 0; q < 4; ++q) {
      uint32_t a = 0u, b2 = (uint32_t)(j0 + q);
      tf2x32(k0, k1, a, b2);
      uint32_t bits = a ^ b2;
      float u = __uint_as_float((bits >> 9) | 0x3f800000u) - 1.0f;
      xn[q] = (u < 0.9f) ? h[q] * (1.0f / 0.9f) : 0.0f;
    }
    __half2 n0 = __floats2half2_rn(xn[0], xn[1]);
    __half2 n1 = __floats2half2_rn(xn[2], xn[3]);
    ux2 nu;
    nu.x = *(const uint32_t*)&n0;
    nu.y = *(const uint32_t*)&n1;
    __builtin_nontemporal_store(nu, (ux2*)xout + xi);
  }
}

// ---------------- layer-3: SpMM + residual + dropout + final mean ----------------
// out = 0.25 * (p + x1 + x2 + x3), x3 computed in registers
__global__ __launch_bounds__(512, 6) void spmm_drop_final(
    const int* __restrict__ boffs, const uint32_t* __restrict__ ep,
    const uint2* __restrict__ T, const uint2* __restrict__ x1,
    const uint2* __restrict__ x2, const float* __restrict__ p,
    float* __restrict__ out, uint32_t k0, uint32_t k1, int nrows, int grow_base) {
  const int w = threadIdx.x >> 6, lane = threadIdx.x & 63;
  const int r0 = blockIdx.x * RPB + w * RPW;
  PHASE_ACCUM(T)
#pragma unroll
  for (int k = 0; k < RPW; ++k) {
    int r = r0 + k;
    if (r >= nrows) break;
    size_t xi = (size_t)r * 64 + lane;
    ux2 x2u = __builtin_nontemporal_load((const ux2*)x2 + xi);
    float2 q0 = h2f(x2u.x), q1 = h2f(x2u.y);
    float h[4] = {acc[k].x + q0.x, acc[k].y + q0.y, acc[k].z + q1.x, acc[k].w + q1.y};
    int j0 = r * DD + lane * 4;
    float xn[4];
#pragma unroll
    for (int q = 0; q < 4; ++q) {
      uint32_t a = 0u, b2 = (uint32_t)(j0 + q);
      tf2x32(k0, k1, a, b2);
      uint32_t bits = a ^ b2;
      float u = __uint_as_float((bits >> 9) | 0x3f800000u) - 1.0f;
      xn[q] = (u < 0.9f) ? h[q] * (1.0f / 0.9f) : 0.0f;
    }
    ux2 x1u = __builtin_nontemporal_load((const ux2*)x1 + xi);
    float2 a0 = h2f(x1u.x), a1 = h2f(x1u.y);
    fx4 pv = __builtin_nontemporal_load((const fx4*)p + xi);
    fx4 ov;
    ov.x = 0.25f * (pv.x + a0.x + q0.x + xn[0]);
    ov.y = 0.25f * (pv.y + a0.y + q0.y + xn[1]);
    ov.z = 0.25f * (pv.z + a1.x + q1.x + xn[2]);
    ov.w = 0.25f * (pv.w + a1.y + q1.y + xn[3]);
    __builtin_nontemporal_store(ov, (fx4*)out + xi);
  }
}

extern "C" void kernel_launch(void* const* d_in, const int* in_sizes, int n_in,
                              void* d_out, int out_size, void* d_ws, size_t ws_size,
                              hipStream_t stream) {
  const float* p     = (const float*)d_in[0];
  const int*   s_row = (const int*)d_in[1];
  const int*   s_col = (const int*)d_in[2];
  const float* s_val = (const float*)d_in[3];
  const int*   t_row = (const int*)d_in[4];
  const int*   t_col = (const int*)d_in[5];
  const float* t_val = (const float*)d_in[6];

  const int nnz_s = in_sizes[1];
  const int nnz_t = in_sizes[4];
  const int N = in_sizes[0] / DD;   // 50000 pois
  const int H = 50000;              // num_hyperedges (problem constant)
  const int slots = H + N;
  const int nnz_all = nnz_t + nnz_s;

  // ---- workspace carve ----
  uint2*    x0      = (uint2*)d_ws;                      // [N*64] 25.6 MB
  uint2*    x1      = x0 + (size_t)N * 64;               // 25.6 MB
  uint2*    th      = x1 + (size_t)N * 64;               // [H*64] 25.6 MB
  uint64_t* staging = (uint64_t*)(th + (size_t)H * 64);  // [nnz_all] 25.6 MB
  uint2*    x2      = (uint2*)staging;                   // aliases staging (dead after build)
  uint32_t* epk     = (uint32_t*)(staging + nnz_all);    // [nnz_all] 12.8 MB
  int*      boffs   = (int*)(epk + nnz_all);             // [slots*BPS] 6.4 MB
  int*      gbcnt   = boffs + (size_t)slots * BPS;       // [NB]
  int*      bbase   = gbcnt + NB;                        // [NB+1]
  int*      gcur    = bbase + (NB + 1);                  // [NB]

  float* out = (float*)d_out;

  // ---- build column-sliced bucket CSR ----
  (void)hipMemsetAsync(gbcnt, 0, sizeof(int) * NB, stream);
  const int cblocks = (nnz_all + CHUNK - 1) / CHUNK;
  bucket_hist<<<cblocks, 256, 0, stream>>>(t_row, nnz_t, s_row, nnz_s, gbcnt, H);
  bucket_scan<<<1, 64, 0, stream>>>(gbcnt, bbase, gcur);
  coarse_scatter<<<cblocks, 256, 0, stream>>>(t_row, t_col, t_val, nnz_t,
                                              s_row, s_col, s_val, nnz_s,
                                              gcur, staging, H);
  fine_scatter<<<NB, 256, 0, stream>>>(staging, bbase, boffs, epk, slots);

  // ---- init x0 = fp16(p) ----
  const int total4 = N * DD / 4;
  init_kernel<<<(total4 + 255) / 256, 256, 0, stream>>>(p, (uint32_t*)x0, total4);

  // ---- layer keys ----
  uint32_t key[3][2];
  for (int i = 0; i < 3; ++i) {
    uint32_t a = 0u, b = (uint32_t)i;
    tf2x32(0u, 42u, a, b);
    key[i][0] = a; key[i][1] = b;
  }

  const int gH = (H + RPB - 1) / RPB;   // 695
  const int gN = (N + RPB - 1) / RPB;   // 695

  // L1
  spmm_phase<<<gH, 512, 0, stream>>>(boffs, epk, x0, th, H, 0);
  spmm_drop_phase<<<gN, 512, 0, stream>>>(boffs, epk, th, x0, x1,
                                          key[0][0], key[0][1], N, H);
  // L2
  spmm_phase<<<gH, 512, 0, stream>>>(boffs, epk, x1, th, H, 0);
  spmm_drop_phase<<<gN, 512, 0, stream>>>(boffs, epk, th, x1, x2,
                                          key[1][0], key[1][1], N, H);
  // L3 (fused final mean)
  spmm_phase<<<gH, 512, 0, stream>>>(boffs, epk, x2, th, H, 0);
  spmm_drop_final<<<gN, 512, 0, stream>>>(boffs, epk, th, x1, x2, p, out,
                                          key[2][0], key[2][1], N, H);
}

// Round 9
// 1556.289 us; speedup vs baseline: 1.0695x; 1.0695x over previous
//
#include <hip/hip_runtime.h>
#include <hip/hip_fp16.h>
#include <stdint.h>

#define DD 256
#define BK_SHIFT 10            // 1024 slots per bucket
#define NB 98                  // ceil(100000/1024) buckets
#define CHUNK 4096             // edges per coarse-scatter block
#define RPW2 8                 // rows per wave in slice SpMM

// ext_vector types accepted by __builtin_nontemporal_*
typedef float    fx4 __attribute__((ext_vector_type(4)));
typedef uint32_t ux2 __attribute__((ext_vector_type(2)));

// ---------------- Threefry-2x32 (bit-exact JAX) ----------------
__host__ __device__ __forceinline__ uint32_t rotl32(uint32_t v, int r) {
  return (v << r) | (v >> (32 - r));
}

__host__ __device__ inline void tf2x32(uint32_t k0, uint32_t k1,
                                       uint32_t& x0, uint32_t& x1) {
  uint32_t ks0 = k0, ks1 = k1, ks2 = k0 ^ k1 ^ 0x1BD11BDAu;
  x0 += ks0; x1 += ks1;
#define TF_RND(r) { x0 += x1; x1 = rotl32(x1, (r)); x1 ^= x0; }
  TF_RND(13) TF_RND(15) TF_RND(26) TF_RND(6)
  x0 += ks1; x1 += ks2 + 1u;
  TF_RND(17) TF_RND(29) TF_RND(16) TF_RND(24)
  x0 += ks2; x1 += ks0 + 2u;
  TF_RND(13) TF_RND(15) TF_RND(26) TF_RND(6)
  x0 += ks0; x1 += ks1 + 3u;
  TF_RND(17) TF_RND(29) TF_RND(16) TF_RND(24)
  x0 += ks1; x1 += ks2 + 4u;
  TF_RND(13) TF_RND(15) TF_RND(26) TF_RND(6)
  x0 += ks2; x1 += ks0 + 5u;
#undef TF_RND
}

__device__ __forceinline__ float2 h2f(uint32_t u) {
  __half2 h = *(__half2*)&u;
  return __half22float2(h);
}

// ---------------- init: x0 = fp16(p) in slice-major [8][N][8xuint2] ----------------
__global__ void init_kernel(const float* __restrict__ p, uint2* __restrict__ xh,
                            int N) {
  int t = blockIdx.x * blockDim.x + threadIdx.x;
  if (t >= N * 64) return;
  int r = t >> 6, part4 = t & 63;           // part4 = s*8 + part
  int s = part4 >> 3, part = part4 & 7;
  fx4 v = __builtin_nontemporal_load((const fx4*)p + t);
  __half2 h0 = __floats2half2_rn(v.x, v.y);
  __half2 h1 = __floats2half2_rn(v.z, v.w);
  uint2 u;
  u.x = *(const uint32_t*)&h0;
  u.y = *(const uint32_t*)&h1;
  xh[(size_t)s * N * 8 + (size_t)r * 8 + part] = u;
}

// ---------------- K1: bucket histogram (LDS-aggregated) ----------------
__global__ __launch_bounds__(256) void bucket_hist(
    const int* __restrict__ t_row, int nnz_t,
    const int* __restrict__ s_row, int nnz_s,
    int* __restrict__ gbcnt, int H) {
  __shared__ int lcnt[NB];
  for (int i = threadIdx.x; i < NB; i += 256) lcnt[i] = 0;
  __syncthreads();
  const int base = blockIdx.x * CHUNK;
  const int nnz_all = nnz_t + nnz_s;
#pragma unroll
  for (int k = 0; k < CHUNK / 256; ++k) {
    int e = base + k * 256 + threadIdx.x;
    if (e < nnz_all) {
      int slot = (e < nnz_t) ? t_row[e] : (H + s_row[e - nnz_t]);
      atomicAdd(&lcnt[slot >> BK_SHIFT], 1);
    }
  }
  __syncthreads();
  for (int i = threadIdx.x; i < NB; i += 256)
    if (lcnt[i]) atomicAdd(&gbcnt[i], lcnt[i]);
}

// ---------------- K2: bucket scan + cursor init ----------------
__global__ void bucket_scan(const int* __restrict__ gbcnt,
                            int* __restrict__ bbase, int* __restrict__ gcur) {
  if (threadIdx.x == 0) {
    int run = 0;
    for (int i = 0; i < NB; ++i) { bbase[i] = run; gcur[i] = run; run += gbcnt[i]; }
    bbase[NB] = run;
  }
}

// ---------------- K3: coarse scatter into bucket-major staging ----------------
// record = (slot << 32) | (col16 << 16) | val_fp16
__global__ __launch_bounds__(256) void coarse_scatter(
    const int* __restrict__ t_row, const int* __restrict__ t_col,
    const float* __restrict__ t_val, int nnz_t,
    const int* __restrict__ s_row, const int* __restrict__ s_col,
    const float* __restrict__ s_val, int nnz_s,
    int* __restrict__ gcur, uint64_t* __restrict__ staging, int H) {
  __shared__ int lcnt[NB], lbase[NB], gofs[NB];
  __shared__ int ltotal;
  __shared__ uint64_t stage[CHUNK];
  const int tid = threadIdx.x;
  for (int i = tid; i < NB; i += 256) lcnt[i] = 0;
  __syncthreads();
  const int base = blockIdx.x * CHUNK;
  const int nnz_all = nnz_t + nnz_s;
  uint64_t rec[CHUNK / 256];
#pragma unroll
  for (int k = 0; k < CHUNK / 256; ++k) {
    int e = base + k * 256 + tid;
    if (e < nnz_all) {
      int slot, col; float val;
      if (e < nnz_t) { slot = t_row[e]; col = t_col[e]; val = t_val[e]; }
      else { int i2 = e - nnz_t; slot = H + s_row[i2]; col = s_col[i2]; val = s_val[i2]; }
      uint32_t packed = ((uint32_t)col << 16) |
                        (uint32_t)__half_as_ushort(__float2half_rn(val));
      rec[k] = ((uint64_t)(uint32_t)slot << 32) | packed;
      atomicAdd(&lcnt[slot >> BK_SHIFT], 1);
    } else {
      rec[k] = ~0ull;
    }
  }
  __syncthreads();
  if (tid == 0) {
    int run = 0;
    for (int i = 0; i < NB; ++i) { lbase[i] = run; run += lcnt[i]; }
    ltotal = run;
  }
  __syncthreads();
  if (tid < NB) {
    if (lcnt[tid]) gofs[tid] = atomicAdd(&gcur[tid], lcnt[tid]);
    lcnt[tid] = 0;
  }
  __syncthreads();
#pragma unroll
  for (int k = 0; k < CHUNK / 256; ++k) {
    int slot = (int)(rec[k] >> 32);
    if (slot >= 0) {
      int b = slot >> BK_SHIFT;
      int p = atomicAdd(&lcnt[b], 1);
      stage[lbase[b] + p] = rec[k];
    }
  }
  __syncthreads();
  const int tot = ltotal;
  for (int i = tid; i < tot; i += 256) {
    uint64_t r = stage[i];
    int b = (int)(r >> 32) >> BK_SHIFT;
    staging[(size_t)gofs[b] + (i - lbase[b])] = r;
  }
}

// ---------------- K4: fine scatter (one block per bucket, L2-local) ----------------
__global__ __launch_bounds__(256) void fine_scatter(
    const uint64_t* __restrict__ staging, const int* __restrict__ bbase,
    int* __restrict__ offs, uint32_t* __restrict__ epk, int slots) {
  __shared__ int scnt[1024];
  __shared__ int sofs[1024];
  __shared__ int wsum[4];
  const int b = blockIdx.x;
  const int bb = bbase[b], be = bbase[b + 1];
  const int tid = threadIdx.x;
  for (int i = tid; i < 1024; i += 256) scnt[i] = 0;
  __syncthreads();
  for (int i = bb + tid; i < be; i += 256)
    atomicAdd(&scnt[(int)(staging[i] >> 32) & 1023], 1);
  __syncthreads();
  const int base4 = tid * 4;
  int v[4], pre[4];
#pragma unroll
  for (int k = 0; k < 4; ++k) v[k] = scnt[base4 + k];
  int tsum = 0;
#pragma unroll
  for (int k = 0; k < 4; ++k) { pre[k] = tsum; tsum += v[k]; }
  int lane = tid & 63, wv = tid >> 6;
  int inc = tsum;
  for (int off = 1; off < 64; off <<= 1) {
    int up = __shfl_up(inc, off, 64);
    if (lane >= off) inc += up;
  }
  if (lane == 63) wsum[wv] = inc;
  __syncthreads();
  int wbase = 0;
  for (int w = 0; w < wv; ++w) wbase += wsum[w];
  int texc = wbase + inc - tsum;
#pragma unroll
  for (int k = 0; k < 4; ++k) sofs[base4 + k] = texc + pre[k];
  __syncthreads();
#pragma unroll
  for (int k = 0; k < 4; ++k) {
    int g = (b << BK_SHIFT) + base4 + k;
    if (g < slots) offs[g] = bb + sofs[base4 + k] + v[k];   // row END
  }
  __syncthreads();
  for (int i = bb + tid; i < be; i += 256) {
    uint64_t r = staging[i];
    int ls = (int)(r >> 32) & 1023;
    int p = atomicAdd(&sofs[ls], 1);
    epk[(size_t)bb + p] = (uint32_t)r;
  }
}

// ---------------- slice gather: one row, 8 edges/instr, 4 dims/lane ----------------
__device__ __forceinline__ float4 gather_slice(
    const int* __restrict__ offs, const uint32_t* __restrict__ ep,
    const uint2* __restrict__ Xs, int g, int sub, int part) {
  int b = (g == 0) ? 0 : __builtin_nontemporal_load(offs + g - 1);
  int e = __builtin_nontemporal_load(offs + g);
  float4 acc = make_float4(0.f, 0.f, 0.f, 0.f);
  for (int i = b; i < e; i += 16) {
    int i0 = i + sub, i1 = i + 8 + sub;
    uint32_t E0 = (i0 < e) ? __builtin_nontemporal_load(ep + i0) : 0u;
    uint32_t E1 = (i1 < e) ? __builtin_nontemporal_load(ep + i1) : 0u;
    uint2 A0 = Xs[(size_t)(E0 >> 16) * 8 + part];
    uint2 A1 = Xs[(size_t)(E1 >> 16) * 8 + part];
    float v0 = __half2float(__ushort_as_half((unsigned short)(E0 & 0xFFFFu)));
    float v1 = __half2float(__ushort_as_half((unsigned short)(E1 & 0xFFFFu)));
    float2 f0 = h2f(A0.x), f1 = h2f(A0.y);
    acc.x += v0 * f0.x; acc.y += v0 * f0.y; acc.z += v0 * f1.x; acc.w += v0 * f1.y;
    f0 = h2f(A1.x); f1 = h2f(A1.y);
    acc.x += v1 * f0.x; acc.y += v1 * f0.y; acc.z += v1 * f1.x; acc.w += v1 * f1.y;
  }
#pragma unroll
  for (int d = 8; d < 64; d <<= 1) {
    acc.x += __shfl_xor(acc.x, d, 64);
    acc.y += __shfl_xor(acc.y, d, 64);
    acc.z += __shfl_xor(acc.z, d, 64);
    acc.w += __shfl_xor(acc.w, d, 64);
  }
  return acc;
}

// ---------------- slice SpMM (plain): Y = A * X ----------------
__global__ __launch_bounds__(256) void spmm_slice(
    const int* __restrict__ offs, const uint32_t* __restrict__ ep,
    const uint2* __restrict__ X, uint2* __restrict__ Y,
    int nrows, int grow_base, int srcN) {
  const int s = blockIdx.x & 7;
  const int rblk = blockIdx.x >> 3;
  const int wid = threadIdx.x >> 6, lane = threadIdx.x & 63;
  const int sub = lane >> 3, part = lane & 7;
  const uint2* Xs = X + (size_t)s * srcN * 8;
  uint2* Ys = Y + (size_t)s * nrows * 8;
  const int rbase = rblk * (4 * RPW2) + wid * RPW2;
#pragma unroll
  for (int k = 0; k < RPW2; ++k) {
    int r = rbase + k;
    if (r >= nrows) return;
    float4 acc = gather_slice(offs, ep, Xs, grow_base + r, sub, part);
    if (sub == 0) {
      __half2 o0 = __floats2half2_rn(acc.x, acc.y);
      __half2 o1 = __floats2half2_rn(acc.z, acc.w);
      uint2 o;
      o.x = *(const uint32_t*)&o0;
      o.y = *(const uint32_t*)&o1;
      Ys[(size_t)r * 8 + part] = o;   // regular store: keep warm in this XCD's L2
    }
  }
}

// ---------------- slice SpMM + residual + dropout (layers 1,2) ----------------
__global__ __launch_bounds__(256) void spmm_drop_slice(
    const int* __restrict__ offs, const uint32_t* __restrict__ ep,
    const uint2* __restrict__ T, const uint2* __restrict__ xprev,
    uint2* __restrict__ xout, uint32_t k0, uint32_t k1,
    int nrows, int grow_base, int srcH) {
  const int s = blockIdx.x & 7;
  const int rblk = blockIdx.x >> 3;
  const int wid = threadIdx.x >> 6, lane = threadIdx.x & 63;
  const int sub = lane >> 3, part = lane & 7;
  const uint2* Ts = T + (size_t)s * srcH * 8;
  const uint2* Xp = xprev + (size_t)s * nrows * 8;
  uint2* Xo = xout + (size_t)s * nrows * 8;
  const int rbase = rblk * (4 * RPW2) + wid * RPW2;
#pragma unroll
  for (int k = 0; k < RPW2; ++k) {
    int r = rbase + k;
    if (r >= nrows) return;
    float4 acc = gather_slice(offs, ep, Ts, grow_base + r, sub, part);
    uint2 xv = Xp[(size_t)r * 8 + part];
    float2 p0 = h2f(xv.x), p1 = h2f(xv.y);
    float h[4] = {acc.x + p0.x, acc.y + p0.y, acc.z + p1.x, acc.w + p1.y};
    int j0 = r * DD + s * 32 + part * 4;
    float xn[4];
#pragma unroll
    for (int q = 0; q < 4; ++q) {
      uint32_t a = 0u, b2 = (uint32_t)(j0 + q);
      tf2x32(k0, k1, a, b2);
      uint32_t bits = a ^ b2;
      float u = __uint_as_float((bits >> 9) | 0x3f800000u) - 1.0f;
      xn[q] = (u < 0.9f) ? h[q] * (1.0f / 0.9f) : 0.0f;
    }
    if (sub == 0) {
      __half2 n0 = __floats2half2_rn(xn[0], xn[1]);
      __half2 n1 = __floats2half2_rn(xn[2], xn[3]);
      uint2 nu;
      nu.x = *(const uint32_t*)&n0;
      nu.y = *(const uint32_t*)&n1;
      Xo[(size_t)r * 8 + part] = nu;
    }
  }
}

// ---------------- layer-3: SpMM + dropout + fused mean ----------------
// out = 0.25 * (p + x1 + x2 + x3), x3 in registers
__global__ __launch_bounds__(256) void spmm_drop_final(
    const int* __restrict__ offs, const uint32_t* __restrict__ ep,
    const uint2* __restrict__ T, const uint2* __restrict__ x1,
    const uint2* __restrict__ x2, const float* __restrict__ p,
    float* __restrict__ out, uint32_t k0, uint32_t k1,
    int nrows, int grow_base, int srcH) {
  const int s = blockIdx.x & 7;
  const int rblk = blockIdx.x >> 3;
  const int wid = threadIdx.x >> 6, lane = threadIdx.x & 63;
  const int sub = lane >> 3, part = lane & 7;
  const uint2* Ts = T + (size_t)s * srcH * 8;
  const uint2* X1 = x1 + (size_t)s * nrows * 8;
  const uint2* X2 = x2 + (size_t)s * nrows * 8;
  const int rbase = rblk * (4 * RPW2) + wid * RPW2;
#pragma unroll
  for (int k = 0; k < RPW2; ++k) {
    int r = rbase + k;
    if (r >= nrows) return;
    float4 acc = gather_slice(offs, ep, Ts, grow_base + r, sub, part);
    uint2 x2u = X2[(size_t)r * 8 + part];
    float2 q0 = h2f(x2u.x), q1 = h2f(x2u.y);
    float h[4] = {acc.x + q0.x, acc.y + q0.y, acc.z + q1.x, acc.w + q1.y};
    int j0 = r * DD + s * 32 + part * 4;
    float xn[4];
#pragma unroll
    for (int q = 0; q < 4; ++q) {
      uint32_t a = 0u, b2 = (uint32_t)(j0 + q);
      tf2x32(k0, k1, a, b2);
      uint32_t bits = a ^ b2;
      float u = __uint_as_float((bits >> 9) | 0x3f800000u) - 1.0f;
      xn[q] = (u < 0.9f) ? h[q] * (1.0f / 0.9f) : 0.0f;
    }
    if (sub == 0) {
      uint2 x1u = X1[(size_t)r * 8 + part];
      float2 a0 = h2f(x1u.x), a1 = h2f(x1u.y);
      size_t oi = (size_t)r * 64 + s * 8 + part;
      fx4 pv = __builtin_nontemporal_load((const fx4*)p + oi);
      fx4 ov;
      ov.x = 0.25f * (pv.x + a0.x + q0.x + xn[0]);
      ov.y = 0.25f * (pv.y + a0.y + q0.y + xn[1]);
      ov.z = 0.25f * (pv.z + a1.x + q1.x + xn[2]);
      ov.w = 0.25f * (pv.w + a1.y + q1.y + xn[3]);
      __builtin_nontemporal_store(ov, (fx4*)out + oi);
    }
  }
}

extern "C" void kernel_launch(void* const* d_in, const int* in_sizes, int n_in,
                              void* d_out, int out_size, void* d_ws, size_t ws_size,
                              hipStream_t stream) {
  const float* p     = (const float*)d_in[0];
  const int*   s_row = (const int*)d_in[1];
  const int*   s_col = (const int*)d_in[2];
  const float* s_val = (const float*)d_in[3];
  const int*   t_row = (const int*)d_in[4];
  const int*   t_col = (const int*)d_in[5];
  const float* t_val = (const float*)d_in[6];

  const int nnz_s = in_sizes[1];
  const int nnz_t = in_sizes[4];
  const int N = in_sizes[0] / DD;   // 50000 pois
  const int H = 50000;              // num_hyperedges (problem constant)
  const int slots = H + N;
  const int nnz_all = nnz_t + nnz_s;

  // ---- workspace carve (all slice-major: [8][rows][8 x uint2]) ----
  uint2*    x0      = (uint2*)d_ws;                      // 25.6 MB
  uint2*    x1      = x0 + (size_t)N * 64;               // 25.6 MB
  uint2*    th      = x1 + (size_t)N * 64;               // 25.6 MB
  uint64_t* staging = (uint64_t*)(th + (size_t)H * 64);  // 25.6 MB
  uint2*    x2      = (uint2*)staging;                   // aliases staging (dead after build)
  uint32_t* epk     = (uint32_t*)(staging + nnz_all);    // 12.8 MB
  int*      offs    = (int*)(epk + nnz_all);             // [slots]
  int*      gbcnt   = offs + slots;                      // [NB]
  int*      bbase   = gbcnt + NB;                        // [NB+1]
  int*      gcur    = bbase + (NB + 1);                  // [NB]

  float* out = (float*)d_out;

  // ---- build bucket-partitioned packed CSR (round-7 proven path) ----
  (void)hipMemsetAsync(gbcnt, 0, sizeof(int) * NB, stream);
  const int cblocks = (nnz_all + CHUNK - 1) / CHUNK;
  bucket_hist<<<cblocks, 256, 0, stream>>>(t_row, nnz_t, s_row, nnz_s, gbcnt, H);
  bucket_scan<<<1, 64, 0, stream>>>(gbcnt, bbase, gcur);
  coarse_scatter<<<cblocks, 256, 0, stream>>>(t_row, t_col, t_val, nnz_t,
                                              s_row, s_col, s_val, nnz_s,
                                              gcur, staging, H);
  fine_scatter<<<NB, 256, 0, stream>>>(staging, bbase, offs, epk, slots);

  // ---- init x0 = fp16(p), slice-major ----
  init_kernel<<<(N * 64 + 255) / 256, 256, 0, stream>>>(p, x0, N);

  // ---- layer keys ----
  uint32_t key[3][2];
  for (int i = 0; i < 3; ++i) {
    uint32_t a = 0u, b = (uint32_t)i;
    tf2x32(0u, 42u, a, b);
    key[i][0] = a; key[i][1] = b;
  }

  const int RPB = 4 * RPW2;                 // 32 rows per block
  const int gH = 8 * ((H + RPB - 1) / RPB); // slice-interleaved grid
  const int gN = 8 * ((N + RPB - 1) / RPB);

  // L1
  spmm_slice<<<gH, 256, 0, stream>>>(offs, epk, x0, th, H, 0, N);
  spmm_drop_slice<<<gN, 256, 0, stream>>>(offs, epk, th, x0, x1,
                                          key[0][0], key[0][1], N, H, H);
  // L2
  spmm_slice<<<gH, 256, 0, stream>>>(offs, epk, x1, th, H, 0, N);
  spmm_drop_slice<<<gN, 256, 0, stream>>>(offs, epk, th, x1, x2,
                                          key[1][0], key[1][1], N, H, H);
  // L3 (fused final mean)
  spmm_slice<<<gH, 256, 0, stream>>>(offs, epk, x2, th, H, 0, N);
  spmm_drop_final<<<gN, 256, 0, stream>>>(offs, epk, th, x1, x2, p, out,
                                          key[2][0], key[2][1], N, H, H);
}

// Round 10
// 815.085 us; speedup vs baseline: 2.0420x; 1.9094x over previous
//
#include <hip/hip_runtime.h>
#include <hip/hip_fp16.h>
#include <stdint.h>

#define DD 256
#define BK_SHIFT 10            // 1024 slots per bucket
#define NB 98                  // ceil(100000/1024) buckets
#define CHUNK 4096             // edges per coarse-scatter block

// ext_vector types accepted by __builtin_nontemporal_*
typedef float    fx4 __attribute__((ext_vector_type(4)));
typedef uint32_t ux2 __attribute__((ext_vector_type(2)));

// ---------------- Threefry-2x32 (bit-exact JAX) ----------------
__host__ __device__ __forceinline__ uint32_t rotl32(uint32_t v, int r) {
  return (v << r) | (v >> (32 - r));
}

__host__ __device__ inline void tf2x32(uint32_t k0, uint32_t k1,
                                       uint32_t& x0, uint32_t& x1) {
  uint32_t ks0 = k0, ks1 = k1, ks2 = k0 ^ k1 ^ 0x1BD11BDAu;
  x0 += ks0; x1 += ks1;
#define TF_RND(r) { x0 += x1; x1 = rotl32(x1, (r)); x1 ^= x0; }
  TF_RND(13) TF_RND(15) TF_RND(26) TF_RND(6)
  x0 += ks1; x1 += ks2 + 1u;
  TF_RND(17) TF_RND(29) TF_RND(16) TF_RND(24)
  x0 += ks2; x1 += ks0 + 2u;
  TF_RND(13) TF_RND(15) TF_RND(26) TF_RND(6)
  x0 += ks0; x1 += ks1 + 3u;
  TF_RND(17) TF_RND(29) TF_RND(16) TF_RND(24)
  x0 += ks1; x1 += ks2 + 4u;
  TF_RND(13) TF_RND(15) TF_RND(26) TF_RND(6)
  x0 += ks2; x1 += ks0 + 5u;
#undef TF_RND
}

__device__ __forceinline__ float2 h2f(uint32_t u) {
  __half2 h = *(__half2*)&u;
  return __half22float2(h);
}

// ---------------- init: x0 = fp16(p) ----------------
__global__ void init_kernel(const float* __restrict__ p, uint32_t* __restrict__ xh,
                            int total4) {
  int t4 = blockIdx.x * blockDim.x + threadIdx.x;
  if (t4 >= total4) return;
  fx4 v = __builtin_nontemporal_load((const fx4*)p + t4);
  __half2 h0 = __floats2half2_rn(v.x, v.y);
  __half2 h1 = __floats2half2_rn(v.z, v.w);
  ux2 u;
  u.x = *(const uint32_t*)&h0;
  u.y = *(const uint32_t*)&h1;
  __builtin_nontemporal_store(u, (ux2*)xh + t4);
}

// ---------------- K1: bucket histogram (LDS-aggregated) ----------------
__global__ __launch_bounds__(256) void bucket_hist(
    const int* __restrict__ t_row, int nnz_t,
    const int* __restrict__ s_row, int nnz_s,
    int* __restrict__ gbcnt, int H) {
  __shared__ int lcnt[NB];
  for (int i = threadIdx.x; i < NB; i += 256) lcnt[i] = 0;
  __syncthreads();
  const int base = blockIdx.x * CHUNK;
  const int nnz_all = nnz_t + nnz_s;
#pragma unroll
  for (int k = 0; k < CHUNK / 256; ++k) {
    int e = base + k * 256 + threadIdx.x;
    if (e < nnz_all) {
      int slot = (e < nnz_t) ? t_row[e] : (H + s_row[e - nnz_t]);
      atomicAdd(&lcnt[slot >> BK_SHIFT], 1);
    }
  }
  __syncthreads();
  for (int i = threadIdx.x; i < NB; i += 256)
    if (lcnt[i]) atomicAdd(&gbcnt[i], lcnt[i]);
}

// ---------------- K2: bucket scan + cursor init ----------------
__global__ void bucket_scan(const int* __restrict__ gbcnt,
                            int* __restrict__ bbase, int* __restrict__ gcur) {
  if (threadIdx.x == 0) {
    int run = 0;
    for (int i = 0; i < NB; ++i) { bbase[i] = run; gcur[i] = run; run += gbcnt[i]; }
    bbase[NB] = run;
  }
}

// ---------------- K3: coarse scatter into bucket-major staging ----------------
// record = (slot << 32) | (col16 << 16) | val_fp16
__global__ __launch_bounds__(256) void coarse_scatter(
    const int* __restrict__ t_row, const int* __restrict__ t_col,
    const float* __restrict__ t_val, int nnz_t,
    const int* __restrict__ s_row, const int* __restrict__ s_col,
    const float* __restrict__ s_val, int nnz_s,
    int* __restrict__ gcur, uint64_t* __restrict__ staging, int H) {
  __shared__ int lcnt[NB], lbase[NB], gofs[NB];
  __shared__ int ltotal;
  __shared__ uint64_t stage[CHUNK];
  const int tid = threadIdx.x;
  for (int i = tid; i < NB; i += 256) lcnt[i] = 0;
  __syncthreads();
  const int base = blockIdx.x * CHUNK;
  const int nnz_all = nnz_t + nnz_s;
  uint64_t rec[CHUNK / 256];
#pragma unroll
  for (int k = 0; k < CHUNK / 256; ++k) {
    int e = base + k * 256 + tid;
    if (e < nnz_all) {
      int slot, col; float val;
      if (e < nnz_t) { slot = t_row[e]; col = t_col[e]; val = t_val[e]; }
      else { int i2 = e - nnz_t; slot = H + s_row[i2]; col = s_col[i2]; val = s_val[i2]; }
      uint32_t packed = ((uint32_t)col << 16) |
                        (uint32_t)__half_as_ushort(__float2half_rn(val));
      rec[k] = ((uint64_t)(uint32_t)slot << 32) | packed;
      atomicAdd(&lcnt[slot >> BK_SHIFT], 1);
    } else {
      rec[k] = ~0ull;
    }
  }
  __syncthreads();
  if (tid == 0) {
    int run = 0;
    for (int i = 0; i < NB; ++i) { lbase[i] = run; run += lcnt[i]; }
    ltotal = run;
  }
  __syncthreads();
  if (tid < NB) {
    if (lcnt[tid]) gofs[tid] = atomicAdd(&gcur[tid], lcnt[tid]);
    lcnt[tid] = 0;
  }
  __syncthreads();
#pragma unroll
  for (int k = 0; k < CHUNK / 256; ++k) {
    int slot = (int)(rec[k] >> 32);
    if (slot >= 0) {
      int b = slot >> BK_SHIFT;
      int p = atomicAdd(&lcnt[b], 1);
      stage[lbase[b] + p] = rec[k];
    }
  }
  __syncthreads();
  const int tot = ltotal;
  for (int i = tid; i < tot; i += 256) {
    uint64_t r = stage[i];
    int b = (int)(r >> 32) >> BK_SHIFT;
    staging[(size_t)gofs[b] + (i - lbase[b])] = r;
  }
}

// ---------------- K4: fine scatter (one block per bucket, L2-local) ----------------
__global__ __launch_bounds__(256) void fine_scatter(
    const uint64_t* __restrict__ staging, const int* __restrict__ bbase,
    int* __restrict__ offs, uint32_t* __restrict__ epk, int slots) {
  __shared__ int scnt[1024];
  __shared__ int sofs[1024];
  __shared__ int wsum[4];
  const int b = blockIdx.x;
  const int bb = bbase[b], be = bbase[b + 1];
  const int tid = threadIdx.x;
  for (int i = tid; i < 1024; i += 256) scnt[i] = 0;
  __syncthreads();
  for (int i = bb + tid; i < be; i += 256)
    atomicAdd(&scnt[(int)(staging[i] >> 32) & 1023], 1);
  __syncthreads();
  const int base4 = tid * 4;
  int v[4], pre[4];
#pragma unroll
  for (int k = 0; k < 4; ++k) v[k] = scnt[base4 + k];
  int tsum = 0;
#pragma unroll
  for (int k = 0; k < 4; ++k) { pre[k] = tsum; tsum += v[k]; }
  int lane = tid & 63, wv = tid >> 6;
  int inc = tsum;
  for (int off = 1; off < 64; off <<= 1) {
    int up = __shfl_up(inc, off, 64);
    if (lane >= off) inc += up;
  }
  if (lane == 63) wsum[wv] = inc;
  __syncthreads();
  int wbase = 0;
  for (int w = 0; w < wv; ++w) wbase += wsum[w];
  int texc = wbase + inc - tsum;
#pragma unroll
  for (int k = 0; k < 4; ++k) sofs[base4 + k] = texc + pre[k];
  __syncthreads();
#pragma unroll
  for (int k = 0; k < 4; ++k) {
    int g = (b << BK_SHIFT) + base4 + k;
    if (g < slots) offs[g] = bb + sofs[base4 + k] + v[k];   // row END
  }
  __syncthreads();
  for (int i = bb + tid; i < be; i += 256) {
    uint64_t r = staging[i];
    int ls = (int)(r >> 32) & 1023;
    int p = atomicAdd(&sofs[ls], 1);
    epk[(size_t)bb + p] = (uint32_t)r;
  }
}

// ---------------- gather SpMM: one wave per row, full D, packed 4B edges ----------------
#define GATHER_BODY(SRC)                                                          \
  float4 acc = make_float4(0.f, 0.f, 0.f, 0.f);                                   \
  int i = b;                                                                      \
  for (; i + 7 < e; i += 8) {                                                     \
    uint32_t E[8]; uint2 A[8];                                                    \
    _Pragma("unroll")                                                             \
    for (int k = 0; k < 8; ++k) E[k] = __builtin_nontemporal_load(ep + i + k);    \
    _Pragma("unroll")                                                             \
    for (int k = 0; k < 8; ++k) A[k] = SRC[(size_t)(E[k] >> 16) * 64 + lane];     \
    _Pragma("unroll")                                                             \
    for (int k = 0; k < 8; ++k) {                                                 \
      float v = __half2float(__ushort_as_half((unsigned short)(E[k] & 0xFFFFu))); \
      float2 f0 = h2f(A[k].x), f1 = h2f(A[k].y);                                  \
      acc.x += v * f0.x; acc.y += v * f0.y;                                       \
      acc.z += v * f1.x; acc.w += v * f1.y;                                       \
    }                                                                             \
  }                                                                               \
  for (; i < e; ++i) {                                                            \
    uint32_t E0 = __builtin_nontemporal_load(ep + i);                             \
    uint2 A0 = SRC[(size_t)(E0 >> 16) * 64 + lane];                               \
    float v = __half2float(__ushort_as_half((unsigned short)(E0 & 0xFFFFu)));     \
    float2 f0 = h2f(A0.x), f1 = h2f(A0.y);                                        \
    acc.x += v * f0.x; acc.y += v * f0.y;                                         \
    acc.z += v * f1.x; acc.w += v * f1.y;                                         \
  }

__global__ __launch_bounds__(256) void spmm_full(
    const int* __restrict__ offs, const uint32_t* __restrict__ ep,
    const uint2* __restrict__ X, uint2* __restrict__ Y, int nrows, int grow_base) {
  int wid = threadIdx.x >> 6, lane = threadIdx.x & 63;
  int r = blockIdx.x * 4 + wid;
  if (r >= nrows) return;
  int g = grow_base + r;
  int b = (g == 0) ? 0 : offs[g - 1];
  int e = offs[g];
  GATHER_BODY(X)
  __half2 o0 = __floats2half2_rn(acc.x, acc.y);
  __half2 o1 = __floats2half2_rn(acc.z, acc.w);
  uint2 o;
  o.x = *(const uint32_t*)&o0;
  o.y = *(const uint32_t*)&o1;
  Y[(size_t)r * 64 + lane] = o;
}

// ---------------- SpMM + residual + dropout -> fp16 x_next (layers 1,2) ----------------
__global__ __launch_bounds__(256) void spmm_drop(
    const int* __restrict__ offs, const uint32_t* __restrict__ ep,
    const uint2* __restrict__ T, const uint2* __restrict__ xprev,
    uint2* __restrict__ xout, uint32_t k0, uint32_t k1, int nrows, int grow_base) {
  int wid = threadIdx.x >> 6, lane = threadIdx.x & 63;
  int r = blockIdx.x * 4 + wid;
  if (r >= nrows) return;
  int g = grow_base + r;
  int b = (g == 0) ? 0 : offs[g - 1];
  int e = offs[g];
  GATHER_BODY(T)
  size_t xi = (size_t)r * 64 + lane;
  ux2 xv_u = __builtin_nontemporal_load((const ux2*)xprev + xi);
  float2 x0f = h2f(xv_u.x), x1f = h2f(xv_u.y);
  float h[4] = {acc.x + x0f.x, acc.y + x0f.y, acc.z + x1f.x, acc.w + x1f.y};
  int j0 = r * DD + lane * 4;
  float xn[4];
#pragma unroll
  for (int k = 0; k < 4; ++k) {
    uint32_t r0 = 0u, r1 = (uint32_t)(j0 + k);
    tf2x32(k0, k1, r0, r1);
    uint32_t bits = r0 ^ r1;
    float u = __uint_as_float((bits >> 9) | 0x3f800000u) - 1.0f;
    xn[k] = (u < 0.9f) ? h[k] * (1.0f / 0.9f) : 0.0f;
  }
  __half2 nx0 = __floats2half2_rn(xn[0], xn[1]);
  __half2 nx1 = __floats2half2_rn(xn[2], xn[3]);
  ux2 nxu;
  nxu.x = *(const uint32_t*)&nx0;
  nxu.y = *(const uint32_t*)&nx1;
  __builtin_nontemporal_store(nxu, (ux2*)xout + xi);
}

// ---------------- layer-3: SpMM + residual + dropout + fused mean ----------------
// out = 0.25 * (x0 + x1 + x2 + x3), x3 in registers (x0 = fp16(p))
__global__ __launch_bounds__(256) void spmm_drop_final(
    const int* __restrict__ offs, const uint32_t* __restrict__ ep,
    const uint2* __restrict__ T, const uint2* __restrict__ x0,
    const uint2* __restrict__ x1, const uint2* __restrict__ x2,
    float* __restrict__ out, uint32_t k0, uint32_t k1, int nrows, int grow_base) {
  int wid = threadIdx.x >> 6, lane = threadIdx.x & 63;
  int r = blockIdx.x * 4 + wid;
  if (r >= nrows) return;
  int g = grow_base + r;
  int b = (g == 0) ? 0 : offs[g - 1];
  int e = offs[g];
  GATHER_BODY(T)
  size_t xi = (size_t)r * 64 + lane;
  ux2 x2u = __builtin_nontemporal_load((const ux2*)x2 + xi);
  float2 q0 = h2f(x2u.x), q1 = h2f(x2u.y);
  float h[4] = {acc.x + q0.x, acc.y + q0.y, acc.z + q1.x, acc.w + q1.y};
  int j0 = r * DD + lane * 4;
  float xn[4];
#pragma unroll
  for (int k = 0; k < 4; ++k) {
    uint32_t r0 = 0u, r1 = (uint32_t)(j0 + k);
    tf2x32(k0, k1, r0, r1);
    uint32_t bits = r0 ^ r1;
    float u = __uint_as_float((bits >> 9) | 0x3f800000u) - 1.0f;
    xn[k] = (u < 0.9f) ? h[k] * (1.0f / 0.9f) : 0.0f;
  }
  ux2 x0u = __builtin_nontemporal_load((const ux2*)x0 + xi);
  ux2 x1u = __builtin_nontemporal_load((const ux2*)x1 + xi);
  float2 p0 = h2f(x0u.x), p1 = h2f(x0u.y);
  float2 a0 = h2f(x1u.x), a1 = h2f(x1u.y);
  fx4 ov;
  ov.x = 0.25f * (p0.x + a0.x + q0.x + xn[0]);
  ov.y = 0.25f * (p0.y + a0.y + q0.y + xn[1]);
  ov.z = 0.25f * (p1.x + a1.x + q1.x + xn[2]);
  ov.w = 0.25f * (p1.y + a1.y + q1.y + xn[3]);
  __builtin_nontemporal_store(ov, (fx4*)out + xi);
}

extern "C" void kernel_launch(void* const* d_in, const int* in_sizes, int n_in,
                              void* d_out, int out_size, void* d_ws, size_t ws_size,
                              hipStream_t stream) {
  const float* p     = (const float*)d_in[0];
  const int*   s_row = (const int*)d_in[1];
  const int*   s_col = (const int*)d_in[2];
  const float* s_val = (const float*)d_in[3];
  const int*   t_row = (const int*)d_in[4];
  const int*   t_col = (const int*)d_in[5];
  const float* t_val = (const float*)d_in[6];

  const int nnz_s = in_sizes[1];
  const int nnz_t = in_sizes[4];
  const int N = in_sizes[0] / DD;   // 50000 pois
  const int H = 50000;              // num_hyperedges (problem constant)
  const int slots = H + N;
  const int nnz_all = nnz_t + nnz_s;

  // ---- workspace carve ----
  uint2*    x0      = (uint2*)d_ws;                      // [N*64] 25.6 MB
  uint2*    x1      = x0 + (size_t)N * 64;               // 25.6 MB
  uint2*    th      = x1 + (size_t)N * 64;               // [H*64] 25.6 MB
  uint64_t* staging = (uint64_t*)(th + (size_t)H * 64);  // [nnz_all] 25.6 MB
  uint2*    x2      = (uint2*)staging;                   // aliases staging (dead after build)
  uint32_t* epk     = (uint32_t*)(staging + nnz_all);    // [nnz_all] 12.8 MB
  int*      offs    = (int*)(epk + nnz_all);             // [slots]
  int*      gbcnt   = offs + slots;                      // [NB]
  int*      bbase   = gbcnt + NB;                        // [NB+1]
  int*      gcur    = bbase + (NB + 1);                  // [NB]

  float* out = (float*)d_out;

  // ---- build bucket-partitioned packed CSR ----
  (void)hipMemsetAsync(gbcnt, 0, sizeof(int) * NB, stream);
  const int cblocks = (nnz_all + CHUNK - 1) / CHUNK;
  bucket_hist<<<cblocks, 256, 0, stream>>>(t_row, nnz_t, s_row, nnz_s, gbcnt, H);
  bucket_scan<<<1, 64, 0, stream>>>(gbcnt, bbase, gcur);
  coarse_scatter<<<cblocks, 256, 0, stream>>>(t_row, t_col, t_val, nnz_t,
                                              s_row, s_col, s_val, nnz_s,
                                              gcur, staging, H);
  fine_scatter<<<NB, 256, 0, stream>>>(staging, bbase, offs, epk, slots);

  // ---- init x0 = fp16(p) ----
  const int total4 = N * DD / 4;
  init_kernel<<<(total4 + 255) / 256, 256, 0, stream>>>(p, (uint32_t*)x0, total4);

  // ---- layer keys ----
  uint32_t key[3][2];
  for (int i = 0; i < 3; ++i) {
    uint32_t a = 0u, b = (uint32_t)i;
    tf2x32(0u, 42u, a, b);
    key[i][0] = a; key[i][1] = b;
  }

  // L1
  spmm_full<<<(H + 3) / 4, 256, 0, stream>>>(offs, epk, x0, th, H, 0);
  spmm_drop<<<(N + 3) / 4, 256, 0, stream>>>(offs, epk, th, x0, x1,
                                             key[0][0], key[0][1], N, H);
  // L2
  spmm_full<<<(H + 3) / 4, 256, 0, stream>>>(offs, epk, x1, th, H, 0);
  spmm_drop<<<(N + 3) / 4, 256, 0, stream>>>(offs, epk, th, x1, x2,
                                             key[1][0], key[1][1], N, H);
  // L3 (fused final mean)
  spmm_full<<<(H + 3) / 4, 256, 0, stream>>>(offs, epk, x2, th, H, 0);
  spmm_drop_final<<<(N + 3) / 4, 256, 0, stream>>>(offs, epk, th, x0, x1, x2, out,
                                                   key[2][0], key[2][1], N, H);
}

// Round 11
// 787.562 us; speedup vs baseline: 2.1134x; 1.0349x over previous
//
#include <hip/hip_runtime.h>
#include <hip/hip_fp16.h>
#include <stdint.h>

#define DD 256
#define BK_SHIFT 10            // 1024 slots per bucket
#define BK_MASK 1023
#define NB 98                  // ceil(100000/1024) buckets
#define SLACK 40960            // per-bucket staging/epk capacity (mean 32.6K)
#define CHUNK 4096             // edges per coarse-scatter block

// ext_vector types accepted by __builtin_nontemporal_*
typedef float    fx4 __attribute__((ext_vector_type(4)));
typedef uint32_t ux2 __attribute__((ext_vector_type(2)));

// ---------------- Threefry-2x32 (bit-exact JAX) ----------------
__host__ __device__ __forceinline__ uint32_t rotl32(uint32_t v, int r) {
  return (v << r) | (v >> (32 - r));
}

__host__ __device__ inline void tf2x32(uint32_t k0, uint32_t k1,
                                       uint32_t& x0, uint32_t& x1) {
  uint32_t ks0 = k0, ks1 = k1, ks2 = k0 ^ k1 ^ 0x1BD11BDAu;
  x0 += ks0; x1 += ks1;
#define TF_RND(r) { x0 += x1; x1 = rotl32(x1, (r)); x1 ^= x0; }
  TF_RND(13) TF_RND(15) TF_RND(26) TF_RND(6)
  x0 += ks1; x1 += ks2 + 1u;
  TF_RND(17) TF_RND(29) TF_RND(16) TF_RND(24)
  x0 += ks2; x1 += ks0 + 2u;
  TF_RND(13) TF_RND(15) TF_RND(26) TF_RND(6)
  x0 += ks0; x1 += ks1 + 3u;
  TF_RND(17) TF_RND(29) TF_RND(16) TF_RND(24)
  x0 += ks1; x1 += ks2 + 4u;
  TF_RND(13) TF_RND(15) TF_RND(26) TF_RND(6)
  x0 += ks2; x1 += ks0 + 5u;
#undef TF_RND
}

__device__ __forceinline__ float2 h2f(uint32_t u) {
  __half2 h = *(__half2*)&u;
  return __half22float2(h);
}

// ---------------- init: x0 = fp16(p) ----------------
__global__ void init_kernel(const float* __restrict__ p, uint32_t* __restrict__ xh,
                            int total4) {
  int t4 = blockIdx.x * blockDim.x + threadIdx.x;
  if (t4 >= total4) return;
  fx4 v = __builtin_nontemporal_load((const fx4*)p + t4);
  __half2 h0 = __floats2half2_rn(v.x, v.y);
  __half2 h1 = __floats2half2_rn(v.z, v.w);
  ux2 u;
  u.x = *(const uint32_t*)&h0;
  u.y = *(const uint32_t*)&h1;
  __builtin_nontemporal_store(u, (ux2*)xh + t4);
}

// ---------------- K0: cursor init (slack-allocated buckets) ----------------
__global__ void gcur_init(int* __restrict__ gcur) {
  int i = blockIdx.x * blockDim.x + threadIdx.x;
  if (i < NB) gcur[i] = i * SLACK;
}

// ---------------- K1: coarse scatter into slack bucket-major staging ----------------
// record = (slot << 32) | (col16 << 16) | val_fp16
__global__ __launch_bounds__(256) void coarse_scatter(
    const int* __restrict__ t_row, const int* __restrict__ t_col,
    const float* __restrict__ t_val, int nnz_t,
    const int* __restrict__ s_row, const int* __restrict__ s_col,
    const float* __restrict__ s_val, int nnz_s,
    int* __restrict__ gcur, uint64_t* __restrict__ staging, int H) {
  __shared__ int lcnt[NB], lbase[NB], gofs[NB];
  __shared__ int ltotal;
  __shared__ uint64_t stage[CHUNK];
  const int tid = threadIdx.x;
  for (int i = tid; i < NB; i += 256) lcnt[i] = 0;
  __syncthreads();
  const int base = blockIdx.x * CHUNK;
  const int nnz_all = nnz_t + nnz_s;
  uint64_t rec[CHUNK / 256];
#pragma unroll
  for (int k = 0; k < CHUNK / 256; ++k) {
    int e = base + k * 256 + tid;
    if (e < nnz_all) {
      int slot, col; float val;
      if (e < nnz_t) { slot = t_row[e]; col = t_col[e]; val = t_val[e]; }
      else { int i2 = e - nnz_t; slot = H + s_row[i2]; col = s_col[i2]; val = s_val[i2]; }
      uint32_t packed = ((uint32_t)col << 16) |
                        (uint32_t)__half_as_ushort(__float2half_rn(val));
      rec[k] = ((uint64_t)(uint32_t)slot << 32) | packed;
      atomicAdd(&lcnt[slot >> BK_SHIFT], 1);
    } else {
      rec[k] = ~0ull;
    }
  }
  __syncthreads();
  if (tid == 0) {
    int run = 0;
    for (int i = 0; i < NB; ++i) { lbase[i] = run; run += lcnt[i]; }
    ltotal = run;
  }
  __syncthreads();
  if (tid < NB) {
    if (lcnt[tid]) gofs[tid] = atomicAdd(&gcur[tid], lcnt[tid]);
    lcnt[tid] = 0;
  }
  __syncthreads();
#pragma unroll
  for (int k = 0; k < CHUNK / 256; ++k) {
    int slot = (int)(rec[k] >> 32);
    if (slot >= 0) {
      int b = slot >> BK_SHIFT;
      int p = atomicAdd(&lcnt[b], 1);
      stage[lbase[b] + p] = rec[k];
    }
  }
  __syncthreads();
  const int tot = ltotal;
  for (int i = tid; i < tot; i += 256) {
    uint64_t r = stage[i];
    int b = (int)(r >> 32) >> BK_SHIFT;
    staging[(size_t)gofs[b] + (i - lbase[b])] = r;
  }
}

// ---------------- K2: fine scatter (one block per bucket, L2-local) ----------------
// offs[g] = absolute END of row g's segment in slacked epk coordinates.
__global__ __launch_bounds__(256) void fine_scatter(
    const uint64_t* __restrict__ staging, const int* __restrict__ gcur,
    int* __restrict__ offs, uint32_t* __restrict__ epk, int slots) {
  __shared__ int scnt[1024];
  __shared__ int sofs[1024];
  __shared__ int wsum[4];
  const int b = blockIdx.x;
  const int bb = b * SLACK;
  const int be = gcur[b];
  const int tid = threadIdx.x;
  for (int i = tid; i < 1024; i += 256) scnt[i] = 0;
  __syncthreads();
  for (int i = bb + tid; i < be; i += 256)
    atomicAdd(&scnt[(int)(staging[i] >> 32) & BK_MASK], 1);
  __syncthreads();
  const int base4 = tid * 4;
  int v[4], pre[4];
#pragma unroll
  for (int k = 0; k < 4; ++k) v[k] = scnt[base4 + k];
  int tsum = 0;
#pragma unroll
  for (int k = 0; k < 4; ++k) { pre[k] = tsum; tsum += v[k]; }
  int lane = tid & 63, wv = tid >> 6;
  int inc = tsum;
  for (int off = 1; off < 64; off <<= 1) {
    int up = __shfl_up(inc, off, 64);
    if (lane >= off) inc += up;
  }
  if (lane == 63) wsum[wv] = inc;
  __syncthreads();
  int wbase = 0;
  for (int w = 0; w < wv; ++w) wbase += wsum[w];
  int texc = wbase + inc - tsum;
#pragma unroll
  for (int k = 0; k < 4; ++k) sofs[base4 + k] = texc + pre[k];
  __syncthreads();
#pragma unroll
  for (int k = 0; k < 4; ++k) {
    int g = (b << BK_SHIFT) + base4 + k;
    if (g < slots) offs[g] = bb + sofs[base4 + k] + v[k];   // absolute row END
  }
  __syncthreads();
  for (int i = bb + tid; i < be; i += 256) {
    uint64_t r = staging[i];
    int ls = (int)(r >> 32) & BK_MASK;
    int p = atomicAdd(&sofs[ls], 1);
    epk[(size_t)bb + p] = (uint32_t)r;
  }
}

// ---------------- gather SpMM: one wave per row, full D, packed 4B edges ----------------
// unroll 16 -> 16 gathers in flight per wave (MLP probe)
#define GB_STEP(NN)                                                               \
  for (; i + (NN - 1) < e; i += NN) {                                             \
    uint32_t E[NN]; uint2 A[NN];                                                  \
    _Pragma("unroll")                                                             \
    for (int k = 0; k < NN; ++k) E[k] = __builtin_nontemporal_load(ep + i + k);   \
    _Pragma("unroll")                                                             \
    for (int k = 0; k < NN; ++k) A[k] = SRC_PTR[(size_t)(E[k] >> 16) * 64 + lane];\
    _Pragma("unroll")                                                             \
    for (int k = 0; k < NN; ++k) {                                                \
      float v = __half2float(__ushort_as_half((unsigned short)(E[k] & 0xFFFFu))); \
      float2 f0 = h2f(A[k].x), f1 = h2f(A[k].y);                                  \
      acc.x += v * f0.x; acc.y += v * f0.y;                                       \
      acc.z += v * f1.x; acc.w += v * f1.y;                                       \
    }                                                                             \
  }

#define GATHER_BODY(SRC)                                                          \
  float4 acc = make_float4(0.f, 0.f, 0.f, 0.f);                                   \
  const uint2* SRC_PTR = (SRC);                                                   \
  int i = b;                                                                      \
  GB_STEP(16)                                                                     \
  GB_STEP(8)                                                                      \
  for (; i < e; ++i) {                                                            \
    uint32_t E0 = __builtin_nontemporal_load(ep + i);                             \
    uint2 A0 = SRC_PTR[(size_t)(E0 >> 16) * 64 + lane];                           \
    float v = __half2float(__ushort_as_half((unsigned short)(E0 & 0xFFFFu)));     \
    float2 f0 = h2f(A0.x), f1 = h2f(A0.y);                                        \
    acc.x += v * f0.x; acc.y += v * f0.y;                                         \
    acc.z += v * f1.x; acc.w += v * f1.y;                                         \
  }

// row segment bounds in slacked epk coordinates
#define ROW_BOUNDS(G)                                                             \
  int b = ((G) & BK_MASK) ? offs[(G) - 1] : ((G) >> BK_SHIFT) * SLACK;            \
  int e = offs[(G)];

__global__ __launch_bounds__(256) void spmm_full(
    const int* __restrict__ offs, const uint32_t* __restrict__ ep,
    const uint2* __restrict__ X, uint2* __restrict__ Y, int nrows, int grow_base) {
  int wid = threadIdx.x >> 6, lane = threadIdx.x & 63;
  int r = blockIdx.x * 4 + wid;
  if (r >= nrows) return;
  int g = grow_base + r;
  ROW_BOUNDS(g)
  GATHER_BODY(X)
  __half2 o0 = __floats2half2_rn(acc.x, acc.y);
  __half2 o1 = __floats2half2_rn(acc.z, acc.w);
  uint2 o;
  o.x = *(const uint32_t*)&o0;
  o.y = *(const uint32_t*)&o1;
  Y[(size_t)r * 64 + lane] = o;
}

// ---------------- SpMM + residual + dropout -> fp16 x_next (layers 1,2) ----------------
__global__ __launch_bounds__(256) void spmm_drop(
    const int* __restrict__ offs, const uint32_t* __restrict__ ep,
    const uint2* __restrict__ T, const uint2* __restrict__ xprev,
    uint2* __restrict__ xout, uint32_t k0, uint32_t k1, int nrows, int grow_base) {
  int wid = threadIdx.x >> 6, lane = threadIdx.x & 63;
  int r = blockIdx.x * 4 + wid;
  if (r >= nrows) return;
  int g = grow_base + r;
  ROW_BOUNDS(g)
  GATHER_BODY(T)
  size_t xi = (size_t)r * 64 + lane;
  ux2 xv_u = __builtin_nontemporal_load((const ux2*)xprev + xi);
  float2 x0f = h2f(xv_u.x), x1f = h2f(xv_u.y);
  float h[4] = {acc.x + x0f.x, acc.y + x0f.y, acc.z + x1f.x, acc.w + x1f.y};
  int j0 = r * DD + lane * 4;
  float xn[4];
#pragma unroll
  for (int k = 0; k < 4; ++k) {
    uint32_t r0 = 0u, r1 = (uint32_t)(j0 + k);
    tf2x32(k0, k1, r0, r1);
    uint32_t bits = r0 ^ r1;
    float u = __uint_as_float((bits >> 9) | 0x3f800000u) - 1.0f;
    xn[k] = (u < 0.9f) ? h[k] * (1.0f / 0.9f) : 0.0f;
  }
  __half2 nx0 = __floats2half2_rn(xn[0], xn[1]);
  __half2 nx1 = __floats2half2_rn(xn[2], xn[3]);
  ux2 nxu;
  nxu.x = *(const uint32_t*)&nx0;
  nxu.y = *(const uint32_t*)&nx1;
  __builtin_nontemporal_store(nxu, (ux2*)xout + xi);
}

// ---------------- layer-3: SpMM + residual + dropout + fused mean ----------------
// out = 0.25 * (x0 + x1 + x2 + x3), x3 in registers (x0 = fp16(p))
__global__ __launch_bounds__(256) void spmm_drop_final(
    const int* __restrict__ offs, const uint32_t* __restrict__ ep,
    const uint2* __restrict__ T, const uint2* __restrict__ x0,
    const uint2* __restrict__ x1, const uint2* __restrict__ x2,
    float* __restrict__ out, uint32_t k0, uint32_t k1, int nrows, int grow_base) {
  int wid = threadIdx.x >> 6, lane = threadIdx.x & 63;
  int r = blockIdx.x * 4 + wid;
  if (r >= nrows) return;
  int g = grow_base + r;
  ROW_BOUNDS(g)
  GATHER_BODY(T)
  size_t xi = (size_t)r * 64 + lane;
  ux2 x2u = __builtin_nontemporal_load((const ux2*)x2 + xi);
  float2 q0 = h2f(x2u.x), q1 = h2f(x2u.y);
  float h[4] = {acc.x + q0.x, acc.y + q0.y, acc.z + q1.x, acc.w + q1.y};
  int j0 = r * DD + lane * 4;
  float xn[4];
#pragma unroll
  for (int k = 0; k < 4; ++k) {
    uint32_t r0 = 0u, r1 = (uint32_t)(j0 + k);
    tf2x32(k0, k1, r0, r1);
    uint32_t bits = r0 ^ r1;
    float u = __uint_as_float((bits >> 9) | 0x3f800000u) - 1.0f;
    xn[k] = (u < 0.9f) ? h[k] * (1.0f / 0.9f) : 0.0f;
  }
  ux2 x0u = __builtin_nontemporal_load((const ux2*)x0 + xi);
  ux2 x1u = __builtin_nontemporal_load((const ux2*)x1 + xi);
  float2 p0 = h2f(x0u.x), p1 = h2f(x0u.y);
  float2 a0 = h2f(x1u.x), a1 = h2f(x1u.y);
  fx4 ov;
  ov.x = 0.25f * (p0.x + a0.x + q0.x + xn[0]);
  ov.y = 0.25f * (p0.y + a0.y + q0.y + xn[1]);
  ov.z = 0.25f * (p1.x + a1.x + q1.x + xn[2]);
  ov.w = 0.25f * (p1.y + a1.y + q1.y + xn[3]);
  __builtin_nontemporal_store(ov, (fx4*)out + xi);
}

extern "C" void kernel_launch(void* const* d_in, const int* in_sizes, int n_in,
                              void* d_out, int out_size, void* d_ws, size_t ws_size,
                              hipStream_t stream) {
  const float* p     = (const float*)d_in[0];
  const int*   s_row = (const int*)d_in[1];
  const int*   s_col = (const int*)d_in[2];
  const float* s_val = (const float*)d_in[3];
  const int*   t_row = (const int*)d_in[4];
  const int*   t_col = (const int*)d_in[5];
  const float* t_val = (const float*)d_in[6];

  const int nnz_s = in_sizes[1];
  const int nnz_t = in_sizes[4];
  const int N = in_sizes[0] / DD;   // 50000 pois
  const int H = 50000;              // num_hyperedges (problem constant)
  const int slots = H + N;
  const int nnz_all = nnz_t + nnz_s;

  // ---- workspace carve ----
  // staging (NB*SLACK uint64 = 32.1 MB) aliases the x1+x2 region (51.2 MB):
  // staging is dead after fine_scatter; x1 first written in L1's spmm_drop,
  // x2 first written in L2's spmm_drop — both after the build completes.
  uint2*    x0      = (uint2*)d_ws;                      // [N*64] 25.6 MB
  uint2*    th      = x0 + (size_t)N * 64;               // [H*64] 25.6 MB
  uint2*    x1      = th + (size_t)H * 64;               // 25.6 MB
  uint2*    x2      = x1 + (size_t)N * 64;               // 25.6 MB
  uint64_t* staging = (uint64_t*)x1;                     // aliases x1+x2 (build only)
  uint32_t* epk     = (uint32_t*)(x2 + (size_t)N * 64);  // [NB*SLACK] 16.1 MB
  int*      offs    = (int*)(epk + (size_t)NB * SLACK);  // [slots]
  int*      gcur    = offs + slots;                      // [NB]

  float* out = (float*)d_out;

  // ---- build slack-bucket packed CSR (no histogram pass) ----
  gcur_init<<<1, 128, 0, stream>>>(gcur);
  const int cblocks = (nnz_all + CHUNK - 1) / CHUNK;
  coarse_scatter<<<cblocks, 256, 0, stream>>>(t_row, t_col, t_val, nnz_t,
                                              s_row, s_col, s_val, nnz_s,
                                              gcur, staging, H);
  fine_scatter<<<NB, 256, 0, stream>>>(staging, gcur, offs, epk, slots);

  // ---- init x0 = fp16(p) ----
  const int total4 = N * DD / 4;
  init_kernel<<<(total4 + 255) / 256, 256, 0, stream>>>(p, (uint32_t*)x0, total4);

  // ---- layer keys ----
  uint32_t key[3][2];
  for (int i = 0; i < 3; ++i) {
    uint32_t a = 0u, b = (uint32_t)i;
    tf2x32(0u, 42u, a, b);
    key[i][0] = a; key[i][1] = b;
  }

  // L1
  spmm_full<<<(H + 3) / 4, 256, 0, stream>>>(offs, epk, x0, th, H, 0);
  spmm_drop<<<(N + 3) / 4, 256, 0, stream>>>(offs, epk, th, x0, x1,
                                             key[0][0], key[0][1], N, H);
  // L2
  spmm_full<<<(H + 3) / 4, 256, 0, stream>>>(offs, epk, x1, th, H, 0);
  spmm_drop<<<(N + 3) / 4, 256, 0, stream>>>(offs, epk, th, x1, x2,
                                             key[1][0], key[1][1], N, H);
  // L3 (fused final mean)
  spmm_full<<<(H + 3) / 4, 256, 0, stream>>>(offs, epk, x2, th, H, 0);
  spmm_drop_final<<<(N + 3) / 4, 256, 0, stream>>>(offs, epk, th, x0, x1, x2, out,
                                                   key[2][0], key[2][1], N, H);
}